// Round 4
// baseline (163.315 us; speedup 1.0000x reference)
//
#include <hip/hip_runtime.h>

// RepeatLayers: variable-length repeat_interleave along axis 0.
// Inputs: d_in[0] = encoder_h float32 [N, D], d_in[1] = repeats int32 [N].
// Output: float32 [total_rows, D], total_rows = sum(repeats) (= out_size / D).
//
// R2/R3: scan kernel's serial global scatter replaced by LDS scatter +
// coalesced sweep; u16 idx map; nontemporal float4 stores in the gather.
// R3 fix: __builtin_nontemporal_store needs a native vector type, not
// HIP_vector_type float4 -> use ext_vector_type(4) float.

typedef float nfloat4 __attribute__((ext_vector_type(4)));

#define SCAN_THREADS 1024
#define ELEMS_PER_THREAD 8   // SCAN_THREADS * ELEMS_PER_THREAD >= N
#define ROWS_PER_BLOCK 8

// ---- Scan + scatter via LDS (used when total_rows*2 fits in 64 KB LDS) ----
__global__ __launch_bounds__(SCAN_THREADS)
void scan_scatter_lds_kernel(const int* __restrict__ repeats,
                             unsigned short* __restrict__ idx_map,
                             int n, int total_rows) {
    extern __shared__ unsigned short lds_idx[];   // total_rows u16
    __shared__ int wsum[SCAN_THREADS / 64];

    const int t = threadIdx.x;
    const int lane = t & 63;
    const int wave = t >> 6;
    const int base = t * ELEMS_PER_THREAD;

    int vals[ELEMS_PER_THREAD];
    int s = 0;
#pragma unroll
    for (int j = 0; j < ELEMS_PER_THREAD; ++j) {
        const int idx = base + j;
        const int v = (idx < n) ? repeats[idx] : 0;
        vals[j] = v;
        s += v;
    }
    // Inclusive wave-scan of per-thread sums (6 shuffle steps).
    int isum = s;
#pragma unroll
    for (int off = 1; off < 64; off <<= 1) {
        const int v = __shfl_up(isum, off, 64);
        if (lane >= off) isum += v;
    }
    if (lane == 63) wsum[wave] = isum;
    __syncthreads();
    if (t == 0) {
        int acc = 0;
#pragma unroll
        for (int w = 0; w < SCAN_THREADS / 64; ++w) {
            const int v = wsum[w];
            wsum[w] = acc;          // exclusive wave prefix
            acc += v;
        }
    }
    __syncthreads();
    int run = wsum[wave] + isum - s;  // exclusive prefix for this thread

    // Scatter into LDS: cheap 2B scattered writes (tiny volume).
#pragma unroll
    for (int j = 0; j < ELEMS_PER_THREAD; ++j) {
        const int src_row = base + j;
        const int r = vals[j];
        for (int k = 0; k < r; ++k) {
            lds_idx[run + k] = (unsigned short)src_row;
        }
        run += r;
    }
    __syncthreads();

    // Coalesced sweep LDS -> global.
    for (int p = t; p < total_rows; p += SCAN_THREADS) {
        idx_map[p] = lds_idx[p];
    }
}

// ---- Fallback: direct global scatter (only if map exceeds LDS) ----
__global__ __launch_bounds__(SCAN_THREADS)
void scan_scatter_global_kernel(const int* __restrict__ repeats,
                                unsigned short* __restrict__ idx_map, int n) {
    __shared__ int wsum[SCAN_THREADS / 64];
    const int t = threadIdx.x;
    const int lane = t & 63;
    const int wave = t >> 6;
    const int base = t * ELEMS_PER_THREAD;

    int vals[ELEMS_PER_THREAD];
    int s = 0;
#pragma unroll
    for (int j = 0; j < ELEMS_PER_THREAD; ++j) {
        const int idx = base + j;
        const int v = (idx < n) ? repeats[idx] : 0;
        vals[j] = v;
        s += v;
    }
    int isum = s;
#pragma unroll
    for (int off = 1; off < 64; off <<= 1) {
        const int v = __shfl_up(isum, off, 64);
        if (lane >= off) isum += v;
    }
    if (lane == 63) wsum[wave] = isum;
    __syncthreads();
    if (t == 0) {
        int acc = 0;
#pragma unroll
        for (int w = 0; w < SCAN_THREADS / 64; ++w) {
            const int v = wsum[w];
            wsum[w] = acc;
            acc += v;
        }
    }
    __syncthreads();
    int run = wsum[wave] + isum - s;
#pragma unroll
    for (int j = 0; j < ELEMS_PER_THREAD; ++j) {
        const int src_row = base + j;
        const int r = vals[j];
        for (int k = 0; k < r; ++k) {
            idx_map[run + k] = (unsigned short)src_row;
        }
        run += r;
    }
}

// ---- Gather: pure streaming row copy ----
__global__ __launch_bounds__(256)
void gather_rows_kernel(const nfloat4* __restrict__ h,
                        const unsigned short* __restrict__ idx_map,
                        nfloat4* __restrict__ out,
                        int total_rows, int d4 /* = D/4 */) {
    const int row0 = blockIdx.x * ROWS_PER_BLOCK;
    // Broadcast loads of the 8 source-row ids, hoisted for ILP.
    int srcs[ROWS_PER_BLOCK];
#pragma unroll
    for (int r = 0; r < ROWS_PER_BLOCK; ++r) {
        const int row = row0 + r;
        srcs[r] = (row < total_rows) ? (int)idx_map[row] : 0;
    }
#pragma unroll
    for (int r = 0; r < ROWS_PER_BLOCK; ++r) {
        const int row = row0 + r;
        if (row >= total_rows) return;  // rows processed in order
        const nfloat4* __restrict__ src = h + (size_t)srcs[r] * d4;
        nfloat4* __restrict__ dst = out + (size_t)row * d4;
        for (int i = threadIdx.x; i < d4; i += blockDim.x) {
            const nfloat4 v = src[i];
            __builtin_nontemporal_store(v, &dst[i]);  // d_out never re-read
        }
    }
}

extern "C" void kernel_launch(void* const* d_in, const int* in_sizes, int n_in,
                              void* d_out, int out_size, void* d_ws, size_t ws_size,
                              hipStream_t stream) {
    const float* encoder_h = (const float*)d_in[0];
    const int*   repeats   = (const int*)d_in[1];
    float*       out       = (float*)d_out;

    const int n = in_sizes[1];            // 8192 source rows
    const int d = in_sizes[0] / n;        // 1024 features
    const int total_rows = out_size / d;  // sum(repeats)

    unsigned short* idx_map = (unsigned short*)d_ws;

    const size_t lds_bytes = ((size_t)total_rows * 2 + 3) & ~(size_t)3;
    if (lds_bytes <= 64 * 1024) {
        scan_scatter_lds_kernel<<<1, SCAN_THREADS, lds_bytes, stream>>>(
            repeats, idx_map, n, total_rows);
    } else {
        scan_scatter_global_kernel<<<1, SCAN_THREADS, 0, stream>>>(
            repeats, idx_map, n);
    }

    const int nblocks = (total_rows + ROWS_PER_BLOCK - 1) / ROWS_PER_BLOCK;
    gather_rows_kernel<<<nblocks, 256, 0, stream>>>(
        (const nfloat4*)encoder_h, idx_map, (nfloat4*)out, total_rows, d / 4);
}

// Round 5
// 155.302 us; speedup vs baseline: 1.0516x; 1.0516x over previous
//
#include <hip/hip_runtime.h>

// RepeatLayers: variable-length repeat_interleave along axis 0.
// Inputs: d_in[0] = encoder_h float32 [N, D], d_in[1] = repeats int32 [N].
// Output: float32 [total_rows, D], total_rows = sum(repeats) (= out_size / D).
//
// R4 structure (loop inversion): one block per SOURCE row. Block loads its
// row once into registers (1 float4/thread), reads r=repeats[row] and the
// exclusive cumsum offset, then issues r independent contiguous row stores.
//  - no idx_map at all (scan kernel just writes the 8192-entry excl. cumsum)
//  - each source row read from HBM exactly once (32 MB reads, minimal)
//  - r stores of held registers are fully independent -> max write MLP
//  - plain (cached) stores: NT was neutral-to-negative in R2->R4 A/B.

typedef float nfloat4 __attribute__((ext_vector_type(4)));

#define SCAN_THREADS 1024
#define ELEMS_PER_THREAD 8   // SCAN_THREADS * ELEMS_PER_THREAD >= N

// ---- Exclusive cumsum of repeats -> csum_excl[0..n) ----
__global__ __launch_bounds__(SCAN_THREADS)
void scan_kernel(const int* __restrict__ repeats,
                 int* __restrict__ csum_excl, int n) {
    __shared__ int wsum[SCAN_THREADS / 64];
    const int t = threadIdx.x;
    const int lane = t & 63;
    const int wave = t >> 6;
    const int base = t * ELEMS_PER_THREAD;

    int vals[ELEMS_PER_THREAD];
    int s = 0;
#pragma unroll
    for (int j = 0; j < ELEMS_PER_THREAD; ++j) {
        const int idx = base + j;
        const int v = (idx < n) ? repeats[idx] : 0;
        vals[j] = v;
        s += v;
    }
    // Inclusive wave-scan of per-thread sums (6 shuffle steps).
    int isum = s;
#pragma unroll
    for (int off = 1; off < 64; off <<= 1) {
        const int v = __shfl_up(isum, off, 64);
        if (lane >= off) isum += v;
    }
    if (lane == 63) wsum[wave] = isum;
    __syncthreads();
    if (t == 0) {
        int acc = 0;
#pragma unroll
        for (int w = 0; w < SCAN_THREADS / 64; ++w) {
            const int v = wsum[w];
            wsum[w] = acc;          // exclusive wave prefix
            acc += v;
        }
    }
    __syncthreads();
    int run = wsum[wave] + isum - s;  // exclusive prefix at this thread
#pragma unroll
    for (int j = 0; j < ELEMS_PER_THREAD; ++j) {
        const int idx = base + j;
        if (idx < n) csum_excl[idx] = run;
        run += vals[j];
    }
}

// ---- Spread: one block per source row, r independent row stores ----
__global__ __launch_bounds__(256)
void spread_rows_kernel(const nfloat4* __restrict__ h,
                        const int* __restrict__ repeats,
                        const int* __restrict__ csum_excl,
                        nfloat4* __restrict__ out,
                        int d4 /* = D/4 */) {
    const int row = blockIdx.x;
    const int r = repeats[row];      // broadcast scalar load
    if (r == 0) return;
    const int obase = csum_excl[row];  // broadcast scalar load
    const nfloat4* __restrict__ src = h + (size_t)row * d4;
    nfloat4* __restrict__ dst0 = out + (size_t)obase * d4;
    for (int i = threadIdx.x; i < d4; i += blockDim.x) {
        const nfloat4 v = src[i];    // one read per element, ever
        // r independent stores of held registers; addresses known upfront.
        for (int k = 0; k < r; ++k) {
            dst0[(size_t)k * d4 + i] = v;
        }
    }
}

extern "C" void kernel_launch(void* const* d_in, const int* in_sizes, int n_in,
                              void* d_out, int out_size, void* d_ws, size_t ws_size,
                              hipStream_t stream) {
    const float* encoder_h = (const float*)d_in[0];
    const int*   repeats   = (const int*)d_in[1];
    float*       out       = (float*)d_out;

    const int n = in_sizes[1];            // 8192 source rows
    const int d = in_sizes[0] / n;        // 1024 features

    int* csum_excl = (int*)d_ws;          // n ints of scratch

    scan_kernel<<<1, SCAN_THREADS, 0, stream>>>(repeats, csum_excl, n);
    spread_rows_kernel<<<n, 256, 0, stream>>>(
        (const nfloat4*)encoder_h, repeats, csum_excl, (nfloat4*)out, d / 4);
}

// Round 6
// 150.178 us; speedup vs baseline: 1.0875x; 1.0341x over previous
//
#include <hip/hip_runtime.h>

// RepeatLayers: variable-length repeat_interleave along axis 0.
// Inputs: d_in[0] = encoder_h float32 [N, D], d_in[1] = repeats int32 [N].
// Output: float32 [total_rows, D], total_rows = sum(repeats) (= out_size / D).
//
// R5 structure: one block per 8 SOURCE rows (deep MLP version of R4's
// loop inversion). Each wave hoists metadata (2x int4 broadcast loads),
// then issues 8 independent row loads (global_load_dwordx4 x8 in flight),
// then all ~28 independent row stores. R4's 1-row blocks had a serial
// load->store chain with only one outstanding row load per wave; that,
// not the map lookup, was the gather-side bottleneck.

typedef float nfloat4 __attribute__((ext_vector_type(4)));

#define SCAN_THREADS 1024
#define ELEMS_PER_THREAD 8   // SCAN_THREADS * ELEMS_PER_THREAD >= N
#define CHUNK 8              // source rows per spread block

// ---- Exclusive cumsum of repeats -> csum_excl[0..n) ----
__global__ __launch_bounds__(SCAN_THREADS)
void scan_kernel(const int* __restrict__ repeats,
                 int* __restrict__ csum_excl, int n) {
    __shared__ int wsum[SCAN_THREADS / 64];
    const int t = threadIdx.x;
    const int lane = t & 63;
    const int wave = t >> 6;
    const int base = t * ELEMS_PER_THREAD;

    int vals[ELEMS_PER_THREAD];
    int s = 0;
#pragma unroll
    for (int j = 0; j < ELEMS_PER_THREAD; ++j) {
        const int idx = base + j;
        const int v = (idx < n) ? repeats[idx] : 0;
        vals[j] = v;
        s += v;
    }
    // Inclusive wave-scan of per-thread sums (6 shuffle steps).
    int isum = s;
#pragma unroll
    for (int off = 1; off < 64; off <<= 1) {
        const int v = __shfl_up(isum, off, 64);
        if (lane >= off) isum += v;
    }
    if (lane == 63) wsum[wave] = isum;
    __syncthreads();
    if (t == 0) {
        int acc = 0;
#pragma unroll
        for (int w = 0; w < SCAN_THREADS / 64; ++w) {
            const int v = wsum[w];
            wsum[w] = acc;          // exclusive wave prefix
            acc += v;
        }
    }
    __syncthreads();
    int run = wsum[wave] + isum - s;  // exclusive prefix at this thread
#pragma unroll
    for (int j = 0; j < ELEMS_PER_THREAD; ++j) {
        const int idx = base + j;
        if (idx < n) csum_excl[idx] = run;
        run += vals[j];
    }
}

// ---- Spread: 8 source rows per block, all loads issued before stores ----
__global__ __launch_bounds__(256)
void spread_rows_kernel(const nfloat4* __restrict__ h,
                        const int* __restrict__ repeats,
                        const int* __restrict__ csum_excl,
                        nfloat4* __restrict__ out,
                        int n, int d4 /* = D/4 */) {
    const int rbase = blockIdx.x * CHUNK;

    // Metadata: 2x int4 broadcast loads each (wave-uniform addresses).
    int reps[CHUNK], offs[CHUNK];
    const int4* rp = (const int4*)(repeats + rbase);
    const int4* cp = (const int4*)(csum_excl + rbase);
#pragma unroll
    for (int q = 0; q < CHUNK / 4; ++q) {
        const int4 r4 = rp[q];
        const int4 c4 = cp[q];
        reps[q * 4 + 0] = r4.x; reps[q * 4 + 1] = r4.y;
        reps[q * 4 + 2] = r4.z; reps[q * 4 + 3] = r4.w;
        offs[q * 4 + 0] = c4.x; offs[q * 4 + 1] = c4.y;
        offs[q * 4 + 2] = c4.z; offs[q * 4 + 3] = c4.w;
    }

    // d4 == blockDim.x for this problem (D=1024); keep a stride loop for
    // generality — it runs exactly once.
    for (int i = threadIdx.x; i < d4; i += blockDim.x) {
        // Phase 1: 8 independent row loads, all in flight simultaneously.
        nfloat4 v[CHUNK];
#pragma unroll
        for (int j = 0; j < CHUNK; ++j) {
            v[j] = h[(size_t)(rbase + j) * d4 + i];
        }
        // Phase 2: all stores (avg ~28 per thread), fully independent.
#pragma unroll
        for (int j = 0; j < CHUNK; ++j) {
            const int r = reps[j];
            const size_t obase = (size_t)offs[j];
            for (int k = 0; k < r; ++k) {
                out[(obase + k) * d4 + i] = v[j];
            }
        }
    }
}

extern "C" void kernel_launch(void* const* d_in, const int* in_sizes, int n_in,
                              void* d_out, int out_size, void* d_ws, size_t ws_size,
                              hipStream_t stream) {
    const float* encoder_h = (const float*)d_in[0];
    const int*   repeats   = (const int*)d_in[1];
    float*       out       = (float*)d_out;

    const int n = in_sizes[1];            // 8192 source rows
    const int d = in_sizes[0] / n;        // 1024 features

    int* csum_excl = (int*)d_ws;          // n ints of scratch

    scan_kernel<<<1, SCAN_THREADS, 0, stream>>>(repeats, csum_excl, n);

    const int nblocks = (n + CHUNK - 1) / CHUNK;   // 1024
    spread_rows_kernel<<<nblocks, 256, 0, stream>>>(
        (const nfloat4*)encoder_h, repeats, csum_excl, (nfloat4*)out, n, d / 4);
}

// Round 7
// 144.067 us; speedup vs baseline: 1.1336x; 1.0424x over previous
//
#include <hip/hip_runtime.h>

// RepeatLayers: variable-length repeat_interleave along axis 0.
// Inputs: d_in[0] = encoder_h float32 [N, D], d_in[1] = repeats int32 [N].
// Output: float32 [total_rows, D], total_rows = sum(repeats).
//
// R7: single fused kernel (no scan kernel, no graph dependency edge).
// Each block of CHUNK=4 source rows computes its own output offset by
// redundantly reducing repeats[0..rbase) — ~32 MB aggregate of L2-hit
// reads, ~1 us total — then loads its 4 rows (independent, in flight
// together) and issues all ~14 independent row stores.
// 2048 blocks = 8/CU halves the per-CU load-imbalance tail vs R6's 4/CU.

typedef float nfloat4 __attribute__((ext_vector_type(4)));

#define CHUNK 4
#define BLOCK 256

__global__ __launch_bounds__(BLOCK)
void spread_fused_kernel(const nfloat4* __restrict__ h,
                         const int* __restrict__ repeats,
                         nfloat4* __restrict__ out,
                         int n, int d4 /* = D/4 */) {
    const int rbase = blockIdx.x * CHUNK;
    const int t = threadIdx.x;
    const int lane = t & 63;
    const int wave = t >> 6;

    // ---- exclusive prefix for this block: obase = sum(repeats[0..rbase)) ----
    __shared__ int wpart[BLOCK / 64];
    int local = 0;
    {
        const int nq = rbase >> 2;            // rbase % 4 == 0 (CHUNK=4)
        const int4* rp4 = (const int4*)repeats;
        for (int q = t; q < nq; q += BLOCK) { // <= 8 L2-hit int4 loads/thread
            const int4 v = rp4[q];
            local += v.x + v.y + v.z + v.w;
        }
    }
#pragma unroll
    for (int off = 32; off > 0; off >>= 1)
        local += __shfl_down(local, off, 64);
    if (lane == 0) wpart[wave] = local;
    __syncthreads();
    const int obase = wpart[0] + wpart[1] + wpart[2] + wpart[3];

    // ---- own chunk's repeat counts + local exclusive prefix ----
    int reps[CHUNK];
    if (rbase + CHUNK <= n) {
        const int4 r4 = *(const int4*)(repeats + rbase);
        reps[0] = r4.x; reps[1] = r4.y; reps[2] = r4.z; reps[3] = r4.w;
    } else {
#pragma unroll
        for (int j = 0; j < CHUNK; ++j)
            reps[j] = (rbase + j < n) ? repeats[rbase + j] : 0;
    }
    int offs[CHUNK];
    offs[0] = obase;
#pragma unroll
    for (int j = 1; j < CHUNK; ++j) offs[j] = offs[j - 1] + reps[j - 1];

    // ---- load 4 rows (independent, all in flight), then all stores ----
    for (int i = t; i < d4; i += BLOCK) {   // runs once: d4 == BLOCK == 256
        nfloat4 v[CHUNK];
#pragma unroll
        for (int j = 0; j < CHUNK; ++j) {
            const int row = rbase + j;
            v[j] = (row < n) ? h[(size_t)row * d4 + i] : nfloat4{0, 0, 0, 0};
        }
#pragma unroll
        for (int j = 0; j < CHUNK; ++j) {
            const int r = reps[j];
            nfloat4* __restrict__ dst = out + (size_t)offs[j] * d4 + i;
            for (int k = 0; k < r; ++k) {
                dst[(size_t)k * d4] = v[j];   // contiguous 4 KB row stores
            }
        }
    }
}

extern "C" void kernel_launch(void* const* d_in, const int* in_sizes, int n_in,
                              void* d_out, int out_size, void* d_ws, size_t ws_size,
                              hipStream_t stream) {
    const float* encoder_h = (const float*)d_in[0];
    const int*   repeats   = (const int*)d_in[1];
    float*       out       = (float*)d_out;

    const int n = in_sizes[1];            // 8192 source rows
    const int d = in_sizes[0] / n;        // 1024 features

    const int nblocks = (n + CHUNK - 1) / CHUNK;   // 2048
    spread_fused_kernel<<<nblocks, BLOCK, 0, stream>>>(
        (const nfloat4*)encoder_h, repeats, (nfloat4*)out, n, d / 4);
}